// Round 6
// baseline (77195.331 us; speedup 1.0000x reference)
//
#include <hip/hip_runtime.h>
#include <cstdint>
#include <cstddef>

// Problem constants
#define B_  128
#define T_  512
#define F_  128
#define U_  512
#define G3  1536   // 3*U
#define BU  (B_ * U_)

// Persistent partition: 8 groups (16 batch rows) x 32 WGs (16 units) = 256 WGs.
#define NGRP 8
#define MB   16
#define GN   32
#define UC   16

typedef __attribute__((ext_vector_type(8))) _Float16 half8;
typedef __attribute__((ext_vector_type(4))) float    f32x4;

union HU16 { _Float16 h; unsigned short us; };

__device__ __forceinline__ float sigmoidf_(float x) {
    return 1.0f / (1.0f + __expf(-x));
}

__device__ __forceinline__ void vm_drain() {
    asm volatile("s_waitcnt vmcnt(0)" ::: "memory");
}

// ---- 16 x dwordx4 coherent loads of one 16-row h panel slice (per lane) ----
template<bool LLC>
__device__ __forceinline__ void load_h16(const _Float16* aptr, half8* f) {
    if constexpr (LLC) {
        asm volatile(
            "global_load_dwordx4 %0, %16, off offset:0 sc0 sc1\n\t"
            "global_load_dwordx4 %1, %16, off offset:64 sc0 sc1\n\t"
            "global_load_dwordx4 %2, %16, off offset:128 sc0 sc1\n\t"
            "global_load_dwordx4 %3, %16, off offset:192 sc0 sc1\n\t"
            "global_load_dwordx4 %4, %16, off offset:256 sc0 sc1\n\t"
            "global_load_dwordx4 %5, %16, off offset:320 sc0 sc1\n\t"
            "global_load_dwordx4 %6, %16, off offset:384 sc0 sc1\n\t"
            "global_load_dwordx4 %7, %16, off offset:448 sc0 sc1\n\t"
            "global_load_dwordx4 %8, %16, off offset:512 sc0 sc1\n\t"
            "global_load_dwordx4 %9, %16, off offset:576 sc0 sc1\n\t"
            "global_load_dwordx4 %10, %16, off offset:640 sc0 sc1\n\t"
            "global_load_dwordx4 %11, %16, off offset:704 sc0 sc1\n\t"
            "global_load_dwordx4 %12, %16, off offset:768 sc0 sc1\n\t"
            "global_load_dwordx4 %13, %16, off offset:832 sc0 sc1\n\t"
            "global_load_dwordx4 %14, %16, off offset:896 sc0 sc1\n\t"
            "global_load_dwordx4 %15, %16, off offset:960 sc0 sc1"
            : "=&v"(f[0]), "=&v"(f[1]), "=&v"(f[2]), "=&v"(f[3]),
              "=&v"(f[4]), "=&v"(f[5]), "=&v"(f[6]), "=&v"(f[7]),
              "=&v"(f[8]), "=&v"(f[9]), "=&v"(f[10]), "=&v"(f[11]),
              "=&v"(f[12]), "=&v"(f[13]), "=&v"(f[14]), "=&v"(f[15])
            : "v"((uint64_t)(uintptr_t)aptr)
            : "memory");
    } else {
        asm volatile(
            "global_load_dwordx4 %0, %16, off offset:0 sc0\n\t"
            "global_load_dwordx4 %1, %16, off offset:64 sc0\n\t"
            "global_load_dwordx4 %2, %16, off offset:128 sc0\n\t"
            "global_load_dwordx4 %3, %16, off offset:192 sc0\n\t"
            "global_load_dwordx4 %4, %16, off offset:256 sc0\n\t"
            "global_load_dwordx4 %5, %16, off offset:320 sc0\n\t"
            "global_load_dwordx4 %6, %16, off offset:384 sc0\n\t"
            "global_load_dwordx4 %7, %16, off offset:448 sc0\n\t"
            "global_load_dwordx4 %8, %16, off offset:512 sc0\n\t"
            "global_load_dwordx4 %9, %16, off offset:576 sc0\n\t"
            "global_load_dwordx4 %10, %16, off offset:640 sc0\n\t"
            "global_load_dwordx4 %11, %16, off offset:704 sc0\n\t"
            "global_load_dwordx4 %12, %16, off offset:768 sc0\n\t"
            "global_load_dwordx4 %13, %16, off offset:832 sc0\n\t"
            "global_load_dwordx4 %14, %16, off offset:896 sc0\n\t"
            "global_load_dwordx4 %15, %16, off offset:960 sc0"
            : "=&v"(f[0]), "=&v"(f[1]), "=&v"(f[2]), "=&v"(f[3]),
              "=&v"(f[4]), "=&v"(f[5]), "=&v"(f[6]), "=&v"(f[7]),
              "=&v"(f[8]), "=&v"(f[9]), "=&v"(f[10]), "=&v"(f[11]),
              "=&v"(f[12]), "=&v"(f[13]), "=&v"(f[14]), "=&v"(f[15])
            : "v"((uint64_t)(uintptr_t)aptr)
            : "memory");
    }
}

__device__ __forceinline__ void wait_h16(half8* f) {
    asm volatile(
        "s_waitcnt vmcnt(0)"
        : "+v"(f[0]), "+v"(f[1]), "+v"(f[2]), "+v"(f[3]),
          "+v"(f[4]), "+v"(f[5]), "+v"(f[6]), "+v"(f[7]),
          "+v"(f[8]), "+v"(f[9]), "+v"(f[10]), "+v"(f[11]),
          "+v"(f[12]), "+v"(f[13]), "+v"(f[14]), "+v"(f[15])
        :
        : "memory");
}

// ---- publish 4 consecutive-row f16 values (rows stride 1024 B) ----
template<bool LLC>
__device__ __forceinline__ void store_h4(_Float16* addr, unsigned v0, unsigned v1,
                                         unsigned v2, unsigned v3) {
    if constexpr (LLC)
        asm volatile(
            "global_store_short %0, %1, off sc0 sc1\n\t"
            "global_store_short %0, %2, off offset:1024 sc0 sc1\n\t"
            "global_store_short %0, %3, off offset:2048 sc0 sc1\n\t"
            "global_store_short %0, %4, off offset:3072 sc0 sc1"
            :: "v"((uint64_t)(uintptr_t)addr), "v"(v0), "v"(v1), "v"(v2), "v"(v3)
            : "memory");
    else
        asm volatile(
            "global_store_short %0, %1, off sc0\n\t"
            "global_store_short %0, %2, off offset:1024 sc0\n\t"
            "global_store_short %0, %3, off offset:2048 sc0\n\t"
            "global_store_short %0, %4, off offset:3072 sc0"
            :: "v"((uint64_t)(uintptr_t)addr), "v"(v0), "v"(v1), "v"(v2), "v"(v3)
            : "memory");
}

// Flag stores ALWAYS write through to LLC (sc0 sc1): updates local L2 line on
// the way (same-XCD fast polls see it) and the LLC copy (fallback polls see
// it). Hang-proof regardless of XCD-affinity detection.
__device__ __forceinline__ void flag_set(unsigned* p, unsigned val) {
    asm volatile("global_store_dword %0, %1, off sc0 sc1"
                 :: "v"((uint64_t)(uintptr_t)p), "v"(val) : "memory");
}

template<bool LLC>
__device__ __forceinline__ unsigned flag_get(const unsigned* p) {
    unsigned v;
    if constexpr (LLC)
        asm volatile("global_load_dword %0, %1, off sc0 sc1\n\ts_waitcnt vmcnt(0)"
                     : "=v"(v) : "v"((uint64_t)(uintptr_t)p) : "memory");
    else
        asm volatile("global_load_dword %0, %1, off sc0\n\ts_waitcnt vmcnt(0)"
                     : "=v"(v) : "v"((uint64_t)(uintptr_t)p) : "memory");
    return v;
}

// Fast (local-L2) poll with bounded spin; falls back to LLC polling so a
// mis-detected XCD mapping degrades to slow-but-correct instead of hanging.
template<bool LLC>
__device__ __forceinline__ void poll_flags(const unsigned* base, int lane, unsigned tgt) {
    const unsigned* p = base + (lane & 31);
    if constexpr (!LLC) {
        int spins = 0;
        for (;;) {
            if (__all((int)(flag_get<false>(p) >= tgt))) return;
            if (++spins > 2048) break;
        }
    }
    while (!__all((int)(flag_get<true>(p) >= tgt))) {}
}

// ---------------- cast x to f16 + zero pub/flag state ------------------------
__global__ void cast_init_kernel(const float* __restrict__ x,
                                 _Float16* __restrict__ xh,
                                 _Float16* __restrict__ h1pub,
                                 _Float16* __restrict__ h2pub,
                                 unsigned int* __restrict__ gbar) {
    size_t i      = (size_t)blockIdx.x * blockDim.x + threadIdx.x;
    size_t stride = (size_t)gridDim.x * blockDim.x;
    for (size_t idx = i; idx < (size_t)B_ * T_ * F_; idx += stride)
        xh[idx] = (_Float16)x[idx];
    for (size_t idx = i; idx < (size_t)3 * BU; idx += stride)
        h1pub[idx] = (_Float16)0.f;
    for (size_t idx = i; idx < (size_t)2 * BU; idx += stride)
        h2pub[idx] = (_Float16)0.f;
    if (blockIdx.x == 0)
        for (int idx = threadIdx.x; idx < 2048; idx += blockDim.x)
            gbar[idx] = 0u;
}

// ---------------- transpose+cast weights: (K,1536) f32 -> (1536,K) f16 -------
__global__ void transpose_cast_kernel(const float* __restrict__ in,
                                      _Float16* __restrict__ out, int K) {
    __shared__ float tile[32][33];
    int n0 = blockIdx.x * 32;
    int k0 = blockIdx.y * 32;
    int tx = threadIdx.x, ty = threadIdx.y;   // block (32, 8)
#pragma unroll
    for (int i = 0; i < 4; ++i)
        tile[ty + i * 8][tx] = in[(size_t)(k0 + ty + i * 8) * G3 + (n0 + tx)];
    __syncthreads();
#pragma unroll
    for (int i = 0; i < 4; ++i)
        out[(size_t)(n0 + ty + i * 8) * K + (k0 + tx)] =
            (_Float16)tile[tx][ty + i * 8];
}

// ---------------- GX1 = x @ W1 ----------------------------------------------
__global__ __launch_bounds__(256) void gemm_gx1_kernel(
    const _Float16* __restrict__ xh,
    const _Float16* __restrict__ w1t,
    _Float16* __restrict__ gx1) {
    int bx = blockIdx.x;          // 12288 = 1024 m-blocks * 12 n-blocks
    int mb = bx / 12, nb = bx % 12;
    int wave = threadIdx.x >> 6, lane = threadIdx.x & 63;
    int wm = wave >> 1, wn = wave & 1;
    int am = lane & 15, aq = lane >> 4;

    half8 af[2][4];
#pragma unroll
    for (int mt = 0; mt < 2; ++mt) {
        int mo = mb * 64 + wm * 32 + mt * 16 + am;
        int b = mo & 127, t = mo >> 7;
        const _Float16* ap = xh + ((size_t)b * T_ + t) * F_ + aq * 8;
#pragma unroll
        for (int kc = 0; kc < 4; ++kc)
            af[mt][kc] = *(const half8*)(ap + kc * 32);
    }

#pragma unroll
    for (int nt = 0; nt < 4; ++nt) {
        int n0 = nb * 128 + wn * 64 + nt * 16;
        f32x4 acc0 = {0.f, 0.f, 0.f, 0.f};
        f32x4 acc1 = {0.f, 0.f, 0.f, 0.f};
#pragma unroll
        for (int kc = 0; kc < 4; ++kc) {
            half8 bf = *(const half8*)(w1t + (size_t)(n0 + am) * F_ + kc * 32 + aq * 8);
            acc0 = __builtin_amdgcn_mfma_f32_16x16x32_f16(af[0][kc], bf, acc0, 0, 0, 0);
            acc1 = __builtin_amdgcn_mfma_f32_16x16x32_f16(af[1][kc], bf, acc1, 0, 0, 0);
        }
        int col = lane & 15, rb = (lane >> 4) * 4;
        int mbase0 = mb * 64 + wm * 32 + 0 * 16;
        int mbase1 = mb * 64 + wm * 32 + 1 * 16;
#pragma unroll
        for (int i = 0; i < 4; ++i) {
            gx1[(size_t)(mbase0 + rb + i) * G3 + n0 + col] = (_Float16)acc0[i];
            gx1[(size_t)(mbase1 + rb + i) * G3 + n0 + col] = (_Float16)acc1[i];
        }
    }
}

// ---------------- persistent 2-layer GRU main loop ---------------------------
// wave0: rec1 mfma + in-lane L1 combine + publish h1 + flag1   (r 0..511)
// wave1: gx2 mfma -> scratch                                   (r 1..512)
// wave2: rec2 mfma -> scratch                                  (r 1..512)
// wave3: L2 combine from scratch + publish h2 + flag2          (r 2..513)
// One __syncthreads per round; h1 is 3-deep buffered (WAR-safe: flag1>=r
// proves every WG passed its end-of-round-(r-2) barrier, so all readers of
// h1_{r-3} are done before slot r%3 is overwritten). h2 2-deep is safe via
// wave2's flag2 poll (transitively bounds remote wave2 progress).
template<bool LLC>
__device__ __forceinline__ void gru_loop(
    const _Float16* gx1, const _Float16* u1t, const _Float16* w2t,
    const _Float16* u2t,
    const float* bi1, const float* br1, const float* bi2, const float* br2,
    _Float16* h1pub, _Float16* h2pub, float* h2fin,
    unsigned* flag1, unsigned* flag2, unsigned* myflag1, unsigned* myflag2,
    int row0, int u0, float* scr) {
    const int tid  = threadIdx.x;
    const int wave = tid >> 6, lane = tid & 63;
    const int col  = lane & 15;
    const int rb4  = (lane >> 4) * 4;
    const int am   = lane & 15, aq = lane >> 4;
    const size_t a_elem = (size_t)(row0 + am) * U_ + aq * 8;
    const int u = u0 + col;

    float st[4] = {0.f, 0.f, 0.f, 0.f};     // wave0: h1 state; wave3: h2 state

    if (wave <= 2) {
        // loop-invariant weight fragments (48 half8)
        const _Float16* wsrc = (wave == 0) ? u1t : (wave == 1) ? w2t : u2t;
        half8 bfr[3][16];
#pragma unroll
        for (int g = 0; g < 3; ++g)
#pragma unroll
            for (int kc = 0; kc < 16; ++kc)
                bfr[g][kc] = *(const half8*)(
                    wsrc + (size_t)(g * U_ + u0 + col) * U_ + kc * 32 + aq * 8);

        // wave0 combine constants + gx1 prefetch registers
        float zb = 0.f, rb_ = 0.f, hbi = 0.f, hbr = 0.f;
        _Float16 pgz[4], pgr[4], pgh[4];
        if (wave == 0) {
            zb  = bi1[u] + br1[u];
            rb_ = bi1[U_ + u] + br1[U_ + u];
            hbi = bi1[2 * U_ + u];
            hbr = br1[2 * U_ + u];
            const _Float16* g0 = gx1 + ((size_t)0 * B_ + row0 + rb4) * G3;
#pragma unroll
            for (int i = 0; i < 4; ++i) {
                pgz[i] = g0[(size_t)i * G3 + u];
                pgr[i] = g0[(size_t)i * G3 + U_ + u];
                pgh[i] = g0[(size_t)i * G3 + 2 * U_ + u];
            }
        }

        int wr3 = 0, rd3 = 2;    // h1 slots: write r%3, read (r+2)%3 (=h1_{r-1})
        for (int r = 0; r <= T_ + 1; ++r) {
            bool act = (wave == 0) ? (r < T_) : (r >= 1 && r <= T_);
            if (act) {
                const unsigned* pb  = (wave == 2) ? flag2 : flag1;
                unsigned        tgt = (wave == 2) ? (unsigned)(r - 1) : (unsigned)r;
                poll_flags<LLC>(pb, lane, tgt);

                const _Float16* hsrc = (wave == 2)
                    ? (h2pub + (size_t)(r & 1) * BU)
                    : (h1pub + (size_t)rd3 * BU);
                half8 f[16];
                load_h16<LLC>(hsrc + a_elem, f);
                wait_h16(f);

                f32x4 a0 = {0.f, 0.f, 0.f, 0.f};
                f32x4 a1 = {0.f, 0.f, 0.f, 0.f};
                f32x4 a2 = {0.f, 0.f, 0.f, 0.f};
#pragma unroll
                for (int kc = 0; kc < 16; ++kc) {
                    a0 = __builtin_amdgcn_mfma_f32_16x16x32_f16(f[kc], bfr[0][kc], a0, 0, 0, 0);
                    a1 = __builtin_amdgcn_mfma_f32_16x16x32_f16(f[kc], bfr[1][kc], a1, 0, 0, 0);
                    a2 = __builtin_amdgcn_mfma_f32_16x16x32_f16(f[kc], bfr[2][kc], a2, 0, 0, 0);
                }

                if (wave == 0) {
                    // in-lane layer-1 combine: lane owns (u, rows rb4..rb4+3)
                    unsigned pv[4];
#pragma unroll
                    for (int i = 0; i < 4; ++i) {
                        float z  = sigmoidf_((float)pgz[i] + a0[i] + zb);
                        float rg = sigmoidf_((float)pgr[i] + a1[i] + rb_);
                        float hh = fmaxf(0.f, (float)pgh[i] + hbi + rg * (a2[i] + hbr));
                        st[i] = z * st[i] + (1.f - z) * hh;
                        HU16 c; c.h = (_Float16)st[i]; pv[i] = c.us;
                    }
                    _Float16* dst = h1pub + (size_t)wr3 * BU +
                                    (size_t)(row0 + rb4) * U_ + u;
                    store_h4<LLC>(dst, pv[0], pv[1], pv[2], pv[3]);
                    vm_drain();
                    if (lane == 0) flag_set(myflag1, (unsigned)(r + 1));
                    if (r + 1 < T_) {
                        const _Float16* g = gx1 + ((size_t)(r + 1) * B_ + row0 + rb4) * G3;
#pragma unroll
                        for (int i = 0; i < 4; ++i) {
                            pgz[i] = g[(size_t)i * G3 + u];
                            pgr[i] = g[(size_t)i * G3 + U_ + u];
                            pgh[i] = g[(size_t)i * G3 + 2 * U_ + u];
                        }
                    }
                } else {
                    float* sp = scr + (size_t)(r & 1) * 6 * 272 +
                                (size_t)((wave == 1) ? 0 : 3) * 272;
#pragma unroll
                    for (int i = 0; i < 4; ++i) {
                        sp[0 * 272 + (rb4 + i) * 17 + col] = a0[i];
                        sp[1 * 272 + (rb4 + i) * 17 + col] = a1[i];
                        sp[2 * 272 + (rb4 + i) * 17 + col] = a2[i];
                    }
                }
            }
            __syncthreads();
            wr3 = (wr3 == 2) ? 0 : wr3 + 1;
            rd3 = (rd3 == 2) ? 0 : rd3 + 1;
        }
    } else {
        // wave 3: layer-2 combine
        const float zb2  = bi2[u] + br2[u];
        const float rb2  = bi2[U_ + u] + br2[U_ + u];
        const float hbi2 = bi2[2 * U_ + u];
        const float hbr2 = br2[2 * U_ + u];

        for (int r = 0; r <= T_ + 1; ++r) {
            if (r >= 2) {
                const float* sp = scr + (size_t)((r - 1) & 1) * 6 * 272;
                int s = r - 2;
                unsigned pv[4];
#pragma unroll
                for (int i = 0; i < 4; ++i) {
                    int ro = (rb4 + i) * 17 + col;
                    float xz = sp[0 * 272 + ro];
                    float xr = sp[1 * 272 + ro];
                    float xh = sp[2 * 272 + ro];
                    float rz = sp[3 * 272 + ro];
                    float rr = sp[4 * 272 + ro];
                    float rh = sp[5 * 272 + ro];
                    float z  = sigmoidf_(xz + rz + zb2);
                    float rg = sigmoidf_(xr + rr + rb2);
                    float hh = fmaxf(0.f, xh + hbi2 + rg * (rh + hbr2));
                    st[i] = z * st[i] + (1.f - z) * hh;
                    HU16 c; c.h = (_Float16)st[i]; pv[i] = c.us;
                }
                _Float16* dst = h2pub + (size_t)(s & 1) * BU +
                                (size_t)(row0 + rb4) * U_ + u;
                store_h4<LLC>(dst, pv[0], pv[1], pv[2], pv[3]);
                vm_drain();
                if (lane == 0) flag_set(myflag2, (unsigned)(s + 1));
                if (s == T_ - 1) {
#pragma unroll
                    for (int i = 0; i < 4; ++i)
                        h2fin[(size_t)(row0 + rb4 + i) * U_ + u] = st[i];
                }
            }
            __syncthreads();
        }
    }
}

__global__ __launch_bounds__(256, 1) void gru_persist_kernel(
    const _Float16* __restrict__ gx1,
    const _Float16* __restrict__ u1t,
    const _Float16* __restrict__ w2t,
    const _Float16* __restrict__ u2t,
    const float* __restrict__ bi1, const float* __restrict__ br1,
    const float* __restrict__ bi2, const float* __restrict__ br2,
    _Float16* __restrict__ h1pub,
    _Float16* __restrict__ h2pub,
    float* __restrict__ h2fin,
    unsigned int* __restrict__ gbar) {
    __shared__ float scr[2 * 6 * 16 * 17];   // 13,056 B

    const int tid  = threadIdx.x;
    const int bx   = blockIdx.x;
    const int grp  = bx & 7;
    const int jj   = bx >> 3;
    const int lane = tid & 63;
    const int row0 = grp * MB;
    const int u0   = jj * UC;

    unsigned* cnt   = gbar + (size_t)grp * 64;          // one-time startup barrier
    unsigned* flag1 = gbar + 512  + (size_t)grp * 32;   // per-WG round flags
    unsigned* flag2 = gbar + 1024 + (size_t)grp * 32;
    unsigned* xcds  = gbar + 1536 + (size_t)grp * 32;   // XCC ids

    // ---- one-time XCD-affinity detection (measured, never assumed) ----
    unsigned xcc;
    asm volatile("s_getreg_b32 %0, hwreg(HW_REG_XCC_ID)" : "=s"(xcc));
    if (tid == 0) {
        __hip_atomic_store(xcds + jj, xcc, __ATOMIC_RELAXED, __HIP_MEMORY_SCOPE_AGENT);
        __hip_atomic_fetch_add(cnt, 1u, __ATOMIC_ACQ_REL, __HIP_MEMORY_SCOPE_AGENT);
        while (__hip_atomic_load(cnt, __ATOMIC_ACQUIRE, __HIP_MEMORY_SCOPE_AGENT) < GN) {}
    }
    __syncthreads();
    unsigned v = __hip_atomic_load(xcds + (lane & 31), __ATOMIC_RELAXED,
                                   __HIP_MEMORY_SCOPE_AGENT);
    unsigned v0 = (unsigned)__shfl((int)v, 0, 64);
    int xcd_uniform = __all((int)(v == v0));
    __syncthreads();

    if (xcd_uniform)
        gru_loop<false>(gx1, u1t, w2t, u2t, bi1, br1, bi2, br2,
                        h1pub, h2pub, h2fin, flag1, flag2,
                        flag1 + jj, flag2 + jj, row0, u0, scr);
    else
        gru_loop<true>(gx1, u1t, w2t, u2t, bi1, br1, bi2, br2,
                       h1pub, h2pub, h2fin, flag1, flag2,
                       flag1 + jj, flag2 + jj, row0, u0, scr);
}

// ---------------- head: out = h2_final @ Wd + bd -----------------------------
__global__ void head_kernel(const float* __restrict__ h2fin,
                            const float* __restrict__ Wd,
                            const float* __restrict__ bd,
                            float* __restrict__ out) {
    int b = blockIdx.x;
    int lane = threadIdx.x;   // 64
    float s = 0.f;
#pragma unroll
    for (int u = lane; u < U_; u += 64)
        s += h2fin[(size_t)b * U_ + u] * Wd[u];
#pragma unroll
    for (int off = 32; off > 0; off >>= 1)
        s += __shfl_down(s, off, 64);
    if (lane == 0) out[b] = s + bd[0];
}

// ---------------- launch -----------------------------------------------------
extern "C" void kernel_launch(void* const* d_in, const int* in_sizes, int n_in,
                              void* d_out, int out_size, void* d_ws, size_t ws_size,
                              hipStream_t stream) {
    (void)in_sizes; (void)n_in; (void)out_size; (void)ws_size;

    const float* x   = (const float*)d_in[0];
    const float* W1  = (const float*)d_in[1];
    const float* U1  = (const float*)d_in[2];
    const float* bi1 = (const float*)d_in[3];
    const float* br1 = (const float*)d_in[4];
    const float* W2  = (const float*)d_in[5];
    const float* U2  = (const float*)d_in[6];
    const float* bi2 = (const float*)d_in[7];
    const float* br2 = (const float*)d_in[8];
    const float* Wd  = (const float*)d_in[9];
    const float* bd  = (const float*)d_in[10];

    char* w = (char*)d_ws;
    constexpr size_t OFF_XH   = 0;
    constexpr size_t OFF_W1T  = OFF_XH  + (size_t)B_ * T_ * F_ * 2;
    constexpr size_t OFF_U1T  = OFF_W1T + (size_t)G3 * F_ * 2;
    constexpr size_t OFF_W2T  = OFF_U1T + (size_t)G3 * U_ * 2;
    constexpr size_t OFF_U2T  = OFF_W2T + (size_t)G3 * U_ * 2;
    constexpr size_t OFF_GX1  = OFF_U2T + (size_t)G3 * U_ * 2;
    constexpr size_t OFF_H1P  = OFF_GX1 + (size_t)T_ * B_ * G3 * 2;
    constexpr size_t OFF_H2P  = OFF_H1P + (size_t)3 * BU * 2;
    constexpr size_t OFF_H2F  = OFF_H2P + (size_t)2 * BU * 2;
    constexpr size_t OFF_BAR  = OFF_H2F + (size_t)BU * 4;

    _Float16* xh   = (_Float16*)(w + OFF_XH);
    _Float16* w1t  = (_Float16*)(w + OFF_W1T);
    _Float16* u1t  = (_Float16*)(w + OFF_U1T);
    _Float16* w2t  = (_Float16*)(w + OFF_W2T);
    _Float16* u2t  = (_Float16*)(w + OFF_U2T);
    _Float16* gx1  = (_Float16*)(w + OFF_GX1);
    _Float16* h1p  = (_Float16*)(w + OFF_H1P);
    _Float16* h2p  = (_Float16*)(w + OFF_H2P);
    float*    h2f  = (float*)   (w + OFF_H2F);
    unsigned int* gbar = (unsigned int*)(w + OFF_BAR);

    cast_init_kernel<<<1024, 256, 0, stream>>>(x, xh, h1p, h2p, gbar);

    dim3 tb(32, 8);
    transpose_cast_kernel<<<dim3(48, 4),  tb, 0, stream>>>(W1, w1t, F_);
    transpose_cast_kernel<<<dim3(48, 16), tb, 0, stream>>>(U1, u1t, U_);
    transpose_cast_kernel<<<dim3(48, 16), tb, 0, stream>>>(W2, w2t, U_);
    transpose_cast_kernel<<<dim3(48, 16), tb, 0, stream>>>(U2, u2t, U_);

    gemm_gx1_kernel<<<12288, 256, 0, stream>>>(xh, w1t, gx1);

    gru_persist_kernel<<<256, 256, 0, stream>>>(gx1, u1t, w2t, u2t,
                                                bi1, br1, bi2, br2,
                                                h1p, h2p, h2f, gbar);

    head_kernel<<<128, 64, 0, stream>>>(h2f, Wd, bd, (float*)d_out);
}

// Round 8
// 2960.404 us; speedup vs baseline: 26.0759x; 26.0759x over previous
//
#include <hip/hip_runtime.h>
#include <cstdint>
#include <cstddef>

// Problem constants
#define B_  128
#define T_  512
#define F_  128
#define U_  512
#define G3  1536   // 3*U
#define BU  (B_ * U_)

// Persistent partition: 8 groups (16 batch rows) x 32 WGs (16 units) = 256 WGs.
#define NGRP 8
#define MB   16
#define GN   32
#define UC   16

typedef __attribute__((ext_vector_type(8))) _Float16 half8;
typedef __attribute__((ext_vector_type(4))) float    f32x4;

union HU16 { _Float16 h; unsigned short us; };

__device__ __forceinline__ float sigmoidf_(float x) {
    return 1.0f / (1.0f + __expf(-x));
}

__device__ __forceinline__ void vm_drain() {
    asm volatile("s_waitcnt vmcnt(0)" ::: "memory");
}

// ---- 16 x dwordx4 system-scope loads (LLC; bypasses L1+L2 — proven R4/R6) ----
__device__ __forceinline__ void load_h16(const _Float16* aptr, half8* f) {
    asm volatile(
        "global_load_dwordx4 %0, %16, off offset:0 sc0 sc1\n\t"
        "global_load_dwordx4 %1, %16, off offset:64 sc0 sc1\n\t"
        "global_load_dwordx4 %2, %16, off offset:128 sc0 sc1\n\t"
        "global_load_dwordx4 %3, %16, off offset:192 sc0 sc1\n\t"
        "global_load_dwordx4 %4, %16, off offset:256 sc0 sc1\n\t"
        "global_load_dwordx4 %5, %16, off offset:320 sc0 sc1\n\t"
        "global_load_dwordx4 %6, %16, off offset:384 sc0 sc1\n\t"
        "global_load_dwordx4 %7, %16, off offset:448 sc0 sc1\n\t"
        "global_load_dwordx4 %8, %16, off offset:512 sc0 sc1\n\t"
        "global_load_dwordx4 %9, %16, off offset:576 sc0 sc1\n\t"
        "global_load_dwordx4 %10, %16, off offset:640 sc0 sc1\n\t"
        "global_load_dwordx4 %11, %16, off offset:704 sc0 sc1\n\t"
        "global_load_dwordx4 %12, %16, off offset:768 sc0 sc1\n\t"
        "global_load_dwordx4 %13, %16, off offset:832 sc0 sc1\n\t"
        "global_load_dwordx4 %14, %16, off offset:896 sc0 sc1\n\t"
        "global_load_dwordx4 %15, %16, off offset:960 sc0 sc1"
        : "=&v"(f[0]), "=&v"(f[1]), "=&v"(f[2]), "=&v"(f[3]),
          "=&v"(f[4]), "=&v"(f[5]), "=&v"(f[6]), "=&v"(f[7]),
          "=&v"(f[8]), "=&v"(f[9]), "=&v"(f[10]), "=&v"(f[11]),
          "=&v"(f[12]), "=&v"(f[13]), "=&v"(f[14]), "=&v"(f[15])
        : "v"((uint64_t)(uintptr_t)aptr)
        : "memory");
}

__device__ __forceinline__ void wait_h16(half8* f) {
    asm volatile(
        "s_waitcnt vmcnt(0)"
        : "+v"(f[0]), "+v"(f[1]), "+v"(f[2]), "+v"(f[3]),
          "+v"(f[4]), "+v"(f[5]), "+v"(f[6]), "+v"(f[7]),
          "+v"(f[8]), "+v"(f[9]), "+v"(f[10]), "+v"(f[11]),
          "+v"(f[12]), "+v"(f[13]), "+v"(f[14]), "+v"(f[15])
        :
        : "memory");
}

// ---- publish 4 consecutive-row f16 values (rows stride 1024 B), LLC scope ----
__device__ __forceinline__ void store_h4(_Float16* addr, unsigned v0, unsigned v1,
                                         unsigned v2, unsigned v3) {
    asm volatile(
        "global_store_short %0, %1, off sc0 sc1\n\t"
        "global_store_short %0, %2, off offset:1024 sc0 sc1\n\t"
        "global_store_short %0, %3, off offset:2048 sc0 sc1\n\t"
        "global_store_short %0, %4, off offset:3072 sc0 sc1"
        :: "v"((uint64_t)(uintptr_t)addr), "v"(v0), "v"(v1), "v"(v2), "v"(v3)
        : "memory");
}

// Flags: HIP agent-scope relaxed atomics (compiler-emitted scope bits; these
// made progress in R2/R4 — the only polling primitive PROVEN live on this HW).
__device__ __forceinline__ void flag_set(unsigned* p, unsigned val) {
    __hip_atomic_store(p, val, __ATOMIC_RELAXED, __HIP_MEMORY_SCOPE_AGENT);
}

__device__ __forceinline__ void poll_flags(const unsigned* base, int lane, unsigned tgt) {
    const unsigned* p = base + (lane & 31);
    while (!__all((int)(__hip_atomic_load(p, __ATOMIC_RELAXED,
                                          __HIP_MEMORY_SCOPE_AGENT) >= tgt))) {}
}

// ---------------- cast x to f16 + zero pub/flag state ------------------------
__global__ void cast_init_kernel(const float* __restrict__ x,
                                 _Float16* __restrict__ xh,
                                 _Float16* __restrict__ h1pub,
                                 _Float16* __restrict__ h2pub,
                                 unsigned int* __restrict__ gbar) {
    size_t i      = (size_t)blockIdx.x * blockDim.x + threadIdx.x;
    size_t stride = (size_t)gridDim.x * blockDim.x;
    for (size_t idx = i; idx < (size_t)B_ * T_ * F_; idx += stride)
        xh[idx] = (_Float16)x[idx];
    for (size_t idx = i; idx < (size_t)3 * BU; idx += stride)
        h1pub[idx] = (_Float16)0.f;
    for (size_t idx = i; idx < (size_t)2 * BU; idx += stride)
        h2pub[idx] = (_Float16)0.f;
    if (blockIdx.x == 0)
        for (int idx = threadIdx.x; idx < 2048; idx += blockDim.x)
            gbar[idx] = 0u;
}

// ---------------- transpose+cast weights: (K,1536) f32 -> (1536,K) f16 -------
__global__ void transpose_cast_kernel(const float* __restrict__ in,
                                      _Float16* __restrict__ out, int K) {
    __shared__ float tile[32][33];
    int n0 = blockIdx.x * 32;
    int k0 = blockIdx.y * 32;
    int tx = threadIdx.x, ty = threadIdx.y;   // block (32, 8)
#pragma unroll
    for (int i = 0; i < 4; ++i)
        tile[ty + i * 8][tx] = in[(size_t)(k0 + ty + i * 8) * G3 + (n0 + tx)];
    __syncthreads();
#pragma unroll
    for (int i = 0; i < 4; ++i)
        out[(size_t)(n0 + ty + i * 8) * K + (k0 + tx)] =
            (_Float16)tile[tx][ty + i * 8];
}

// ---------------- GX1 = x @ W1 ----------------------------------------------
__global__ __launch_bounds__(256) void gemm_gx1_kernel(
    const _Float16* __restrict__ xh,
    const _Float16* __restrict__ w1t,
    _Float16* __restrict__ gx1) {
    int bx = blockIdx.x;          // 12288 = 1024 m-blocks * 12 n-blocks
    int mb = bx / 12, nb = bx % 12;
    int wave = threadIdx.x >> 6, lane = threadIdx.x & 63;
    int wm = wave >> 1, wn = wave & 1;
    int am = lane & 15, aq = lane >> 4;

    half8 af[2][4];
#pragma unroll
    for (int mt = 0; mt < 2; ++mt) {
        int mo = mb * 64 + wm * 32 + mt * 16 + am;
        int b = mo & 127, t = mo >> 7;
        const _Float16* ap = xh + ((size_t)b * T_ + t) * F_ + aq * 8;
#pragma unroll
        for (int kc = 0; kc < 4; ++kc)
            af[mt][kc] = *(const half8*)(ap + kc * 32);
    }

#pragma unroll
    for (int nt = 0; nt < 4; ++nt) {
        int n0 = nb * 128 + wn * 64 + nt * 16;
        f32x4 acc0 = {0.f, 0.f, 0.f, 0.f};
        f32x4 acc1 = {0.f, 0.f, 0.f, 0.f};
#pragma unroll
        for (int kc = 0; kc < 4; ++kc) {
            half8 bf = *(const half8*)(w1t + (size_t)(n0 + am) * F_ + kc * 32 + aq * 8);
            acc0 = __builtin_amdgcn_mfma_f32_16x16x32_f16(af[0][kc], bf, acc0, 0, 0, 0);
            acc1 = __builtin_amdgcn_mfma_f32_16x16x32_f16(af[1][kc], bf, acc1, 0, 0, 0);
        }
        int col = lane & 15, rb = (lane >> 4) * 4;
        int mbase0 = mb * 64 + wm * 32 + 0 * 16;
        int mbase1 = mb * 64 + wm * 32 + 1 * 16;
#pragma unroll
        for (int i = 0; i < 4; ++i) {
            gx1[(size_t)(mbase0 + rb + i) * G3 + n0 + col] = (_Float16)acc0[i];
            gx1[(size_t)(mbase1 + rb + i) * G3 + n0 + col] = (_Float16)acc1[i];
        }
    }
}

// ---------------- persistent 2-layer GRU main loop ---------------------------
// wave0: rec1 mfma + in-lane L1 combine + publish h1 + flag1   (r 0..511)
// wave1: gx2 mfma -> scratch                                   (r 1..512)
// wave2: rec2 mfma -> scratch                                  (r 1..512)
// wave3: L2 combine from scratch + publish h2 + flag2          (r 2..513)
// One __syncthreads per round; h1 3-deep (WAR-safe: flag1>=r proves every WG
// passed its end-of-round-(r-2) barrier, so all readers of h1_{r-3} drained
// their loads pre-barrier). h2 2-deep safe: local wave2's flag2>=r-2 poll at
// round r-1 proves remote wave3 reached round r-1 => remote WG passed barrier
// end-of-(r-2) => remote wave2's h2_{r-4} reads are complete.
__global__ __launch_bounds__(256, 1) void gru_persist_kernel(
    const _Float16* __restrict__ gx1,
    const _Float16* __restrict__ u1t,
    const _Float16* __restrict__ w2t,
    const _Float16* __restrict__ u2t,
    const float* __restrict__ bi1, const float* __restrict__ br1,
    const float* __restrict__ bi2, const float* __restrict__ br2,
    _Float16* __restrict__ h1pub,      // 3 x (128,512) f16
    _Float16* __restrict__ h2pub,      // 2 x (128,512) f16
    float* __restrict__ h2fin,         // (128,512) f32
    unsigned int* __restrict__ gbar) {
    __shared__ float scr[2 * 6 * 16 * 17];   // 13,056 B

    const int tid  = threadIdx.x;
    const int bx   = blockIdx.x;
    const int grp  = bx & 7;
    const int jj   = bx >> 3;
    const int wave = tid >> 6, lane = tid & 63;
    const int row0 = grp * MB;
    const int u0   = jj * UC;

    unsigned* flag1 = gbar + 512  + (size_t)grp * 32;   // per-WG round flags
    unsigned* flag2 = gbar + 1024 + (size_t)grp * 32;
    unsigned* myflag1 = flag1 + jj;
    unsigned* myflag2 = flag2 + jj;

    const int col = lane & 15;
    const int rb4 = (lane >> 4) * 4;
    const int aq  = lane >> 4;
    const size_t a_elem = (size_t)(row0 + col) * U_ + aq * 8;
    const int u = u0 + col;

    float st[4] = {0.f, 0.f, 0.f, 0.f};     // wave0: h1 state; wave3: h2 state

    if (wave <= 2) {
        // loop-invariant weight fragments (48 half8; spill to AGPRs is fine)
        const _Float16* wsrc = (wave == 0) ? u1t : (wave == 1) ? w2t : u2t;
        half8 bfr[3][16];
#pragma unroll
        for (int g = 0; g < 3; ++g)
#pragma unroll
            for (int kc = 0; kc < 16; ++kc)
                bfr[g][kc] = *(const half8*)(
                    wsrc + (size_t)(g * U_ + u0 + col) * U_ + kc * 32 + aq * 8);

        // wave0 combine constants + double-buffered gx1 prefetch registers
        float zb = 0.f, rb_ = 0.f, hbi = 0.f, hbr = 0.f;
        _Float16 pgz[4], pgr[4], pgh[4];
        if (wave == 0) {
            zb  = bi1[u] + br1[u];
            rb_ = bi1[U_ + u] + br1[U_ + u];
            hbi = bi1[2 * U_ + u];
            hbr = br1[2 * U_ + u];
            const _Float16* g0 = gx1 + ((size_t)0 * B_ + row0 + rb4) * G3;
#pragma unroll
            for (int i = 0; i < 4; ++i) {
                pgz[i] = g0[(size_t)i * G3 + u];
                pgr[i] = g0[(size_t)i * G3 + U_ + u];
                pgh[i] = g0[(size_t)i * G3 + 2 * U_ + u];
            }
        }

        int wr3 = 0, rd3 = 2;    // h1 slots: write r%3, read (r+2)%3 (=h1_{r-1})
        for (int r = 0; r <= T_ + 1; ++r) {
            bool act = (wave == 0) ? (r < T_) : (r >= 1 && r <= T_);
            if (act) {
                // wave0: issue NEXT round's gx1 prefetch before the poll so its
                // (possibly HBM) latency hides under poll+load+mfma and the
                // end-of-round barrier's vmcnt drain doesn't stall on it.
                _Float16 ngz[4], ngr[4], ngh[4];
                bool pf = (wave == 0) && (r + 1 < T_);
                if (pf) {
                    const _Float16* g = gx1 + ((size_t)(r + 1) * B_ + row0 + rb4) * G3;
#pragma unroll
                    for (int i = 0; i < 4; ++i) {
                        ngz[i] = g[(size_t)i * G3 + u];
                        ngr[i] = g[(size_t)i * G3 + U_ + u];
                        ngh[i] = g[(size_t)i * G3 + 2 * U_ + u];
                    }
                }

                const unsigned* pb  = (wave == 2) ? flag2 : flag1;
                unsigned        tgt = (wave == 2) ? (unsigned)(r - 1) : (unsigned)r;
                poll_flags(pb, lane, tgt);

                const _Float16* hsrc = (wave == 2)
                    ? (h2pub + (size_t)(r & 1) * BU)
                    : (h1pub + (size_t)rd3 * BU);
                half8 f[16];
                load_h16(hsrc + a_elem, f);
                wait_h16(f);

                f32x4 a0 = {0.f, 0.f, 0.f, 0.f};
                f32x4 a1 = {0.f, 0.f, 0.f, 0.f};
                f32x4 a2 = {0.f, 0.f, 0.f, 0.f};
#pragma unroll
                for (int kc = 0; kc < 16; ++kc) {
                    a0 = __builtin_amdgcn_mfma_f32_16x16x32_f16(f[kc], bfr[0][kc], a0, 0, 0, 0);
                    a1 = __builtin_amdgcn_mfma_f32_16x16x32_f16(f[kc], bfr[1][kc], a1, 0, 0, 0);
                    a2 = __builtin_amdgcn_mfma_f32_16x16x32_f16(f[kc], bfr[2][kc], a2, 0, 0, 0);
                }

                if (wave == 0) {
                    // in-lane layer-1 combine: lane owns (u, rows rb4..rb4+3)
                    unsigned pv[4];
#pragma unroll
                    for (int i = 0; i < 4; ++i) {
                        float z  = sigmoidf_((float)pgz[i] + a0[i] + zb);
                        float rg = sigmoidf_((float)pgr[i] + a1[i] + rb_);
                        float hh = fmaxf(0.f, (float)pgh[i] + hbi + rg * (a2[i] + hbr));
                        st[i] = z * st[i] + (1.f - z) * hh;
                        HU16 c; c.h = (_Float16)st[i]; pv[i] = c.us;
                    }
                    _Float16* dst = h1pub + (size_t)wr3 * BU +
                                    (size_t)(row0 + rb4) * U_ + u;
                    store_h4(dst, pv[0], pv[1], pv[2], pv[3]);
                    vm_drain();          // also completes the gx1 prefetch
                    if (lane == 0) flag_set(myflag1, (unsigned)(r + 1));
                    if (pf) {
#pragma unroll
                        for (int i = 0; i < 4; ++i) {
                            pgz[i] = ngz[i]; pgr[i] = ngr[i]; pgh[i] = ngh[i];
                        }
                    }
                } else {
                    float* sp = scr + (size_t)(r & 1) * 6 * 272 +
                                (size_t)((wave == 1) ? 0 : 3) * 272;
#pragma unroll
                    for (int i = 0; i < 4; ++i) {
                        sp[0 * 272 + (rb4 + i) * 17 + col] = a0[i];
                        sp[1 * 272 + (rb4 + i) * 17 + col] = a1[i];
                        sp[2 * 272 + (rb4 + i) * 17 + col] = a2[i];
                    }
                }
            }
            __syncthreads();
            wr3 = (wr3 == 2) ? 0 : wr3 + 1;
            rd3 = (rd3 == 2) ? 0 : rd3 + 1;
        }
    } else {
        // wave 3: layer-2 combine
        const float zb2  = bi2[u] + br2[u];
        const float rb2  = bi2[U_ + u] + br2[U_ + u];
        const float hbi2 = bi2[2 * U_ + u];
        const float hbr2 = br2[2 * U_ + u];

        for (int r = 0; r <= T_ + 1; ++r) {
            if (r >= 2) {
                const float* sp = scr + (size_t)((r - 1) & 1) * 6 * 272;
                int s = r - 2;
                unsigned pv[4];
#pragma unroll
                for (int i = 0; i < 4; ++i) {
                    int ro = (rb4 + i) * 17 + col;
                    float xz = sp[0 * 272 + ro];
                    float xr = sp[1 * 272 + ro];
                    float xh = sp[2 * 272 + ro];
                    float rz = sp[3 * 272 + ro];
                    float rr = sp[4 * 272 + ro];
                    float rh = sp[5 * 272 + ro];
                    float z  = sigmoidf_(xz + rz + zb2);
                    float rg = sigmoidf_(xr + rr + rb2);
                    float hh = fmaxf(0.f, xh + hbi2 + rg * (rh + hbr2));
                    st[i] = z * st[i] + (1.f - z) * hh;
                    HU16 c; c.h = (_Float16)st[i]; pv[i] = c.us;
                }
                _Float16* dst = h2pub + (size_t)(s & 1) * BU +
                                (size_t)(row0 + rb4) * U_ + u;
                store_h4(dst, pv[0], pv[1], pv[2], pv[3]);
                vm_drain();
                if (lane == 0) flag_set(myflag2, (unsigned)(s + 1));
                if (s == T_ - 1) {
#pragma unroll
                    for (int i = 0; i < 4; ++i)
                        h2fin[(size_t)(row0 + rb4 + i) * U_ + u] = st[i];
                }
            }
            __syncthreads();
        }
    }
}

// ---------------- head: out = h2_final @ Wd + bd -----------------------------
__global__ void head_kernel(const float* __restrict__ h2fin,
                            const float* __restrict__ Wd,
                            const float* __restrict__ bd,
                            float* __restrict__ out) {
    int b = blockIdx.x;
    int lane = threadIdx.x;   // 64
    float s = 0.f;
#pragma unroll
    for (int u = lane; u < U_; u += 64)
        s += h2fin[(size_t)b * U_ + u] * Wd[u];
#pragma unroll
    for (int off = 32; off > 0; off >>= 1)
        s += __shfl_down(s, off, 64);
    if (lane == 0) out[b] = s + bd[0];
}

// ---------------- launch -----------------------------------------------------
extern "C" void kernel_launch(void* const* d_in, const int* in_sizes, int n_in,
                              void* d_out, int out_size, void* d_ws, size_t ws_size,
                              hipStream_t stream) {
    (void)in_sizes; (void)n_in; (void)out_size; (void)ws_size;

    const float* x   = (const float*)d_in[0];
    const float* W1  = (const float*)d_in[1];
    const float* U1  = (const float*)d_in[2];
    const float* bi1 = (const float*)d_in[3];
    const float* br1 = (const float*)d_in[4];
    const float* W2  = (const float*)d_in[5];
    const float* U2  = (const float*)d_in[6];
    const float* bi2 = (const float*)d_in[7];
    const float* br2 = (const float*)d_in[8];
    const float* Wd  = (const float*)d_in[9];
    const float* bd  = (const float*)d_in[10];

    char* w = (char*)d_ws;
    constexpr size_t OFF_XH   = 0;
    constexpr size_t OFF_W1T  = OFF_XH  + (size_t)B_ * T_ * F_ * 2;
    constexpr size_t OFF_U1T  = OFF_W1T + (size_t)G3 * F_ * 2;
    constexpr size_t OFF_W2T  = OFF_U1T + (size_t)G3 * U_ * 2;
    constexpr size_t OFF_U2T  = OFF_W2T + (size_t)G3 * U_ * 2;
    constexpr size_t OFF_GX1  = OFF_U2T + (size_t)G3 * U_ * 2;
    constexpr size_t OFF_H1P  = OFF_GX1 + (size_t)T_ * B_ * G3 * 2;
    constexpr size_t OFF_H2P  = OFF_H1P + (size_t)3 * BU * 2;
    constexpr size_t OFF_H2F  = OFF_H2P + (size_t)2 * BU * 2;
    constexpr size_t OFF_BAR  = OFF_H2F + (size_t)BU * 4;

    _Float16* xh   = (_Float16*)(w + OFF_XH);
    _Float16* w1t  = (_Float16*)(w + OFF_W1T);
    _Float16* u1t  = (_Float16*)(w + OFF_U1T);
    _Float16* w2t  = (_Float16*)(w + OFF_W2T);
    _Float16* u2t  = (_Float16*)(w + OFF_U2T);
    _Float16* gx1  = (_Float16*)(w + OFF_GX1);
    _Float16* h1p  = (_Float16*)(w + OFF_H1P);
    _Float16* h2p  = (_Float16*)(w + OFF_H2P);
    float*    h2f  = (float*)   (w + OFF_H2F);
    unsigned int* gbar = (unsigned int*)(w + OFF_BAR);

    cast_init_kernel<<<1024, 256, 0, stream>>>(x, xh, h1p, h2p, gbar);

    dim3 tb(32, 8);
    transpose_cast_kernel<<<dim3(48, 4),  tb, 0, stream>>>(W1, w1t, F_);
    transpose_cast_kernel<<<dim3(48, 16), tb, 0, stream>>>(U1, u1t, U_);
    transpose_cast_kernel<<<dim3(48, 16), tb, 0, stream>>>(W2, w2t, U_);
    transpose_cast_kernel<<<dim3(48, 16), tb, 0, stream>>>(U2, u2t, U_);

    gemm_gx1_kernel<<<12288, 256, 0, stream>>>(xh, w1t, gx1);

    gru_persist_kernel<<<256, 256, 0, stream>>>(gx1, u1t, w2t, u2t,
                                                bi1, br1, bi2, br2,
                                                h1p, h2p, h2f, gbar);

    head_kernel<<<128, 64, 0, stream>>>(h2f, Wd, bd, (float*)d_out);
}

// Round 9
// 1936.850 us; speedup vs baseline: 39.8561x; 1.5285x over previous
//
#include <hip/hip_runtime.h>
#include <cstdint>
#include <cstddef>

// Problem constants
#define B_  128
#define T_  512
#define F_  128
#define U_  512
#define G3  1536   // 3*U
#define BU  (B_ * U_)

// Persistent partition: 8 groups (16 batch rows) x 32 WGs (16 units) = 256 WGs.
#define NGRP 8
#define MB   16
#define GN   32
#define UC   16

typedef __attribute__((ext_vector_type(8))) _Float16 half8;
typedef __attribute__((ext_vector_type(4))) float    f32x4;

union HU16 { _Float16 h; unsigned short us; };

__device__ __forceinline__ float sigmoidf_(float x) {
    return 1.0f / (1.0f + __expf(-x));
}

__device__ __forceinline__ void vm_drain() {
    asm volatile("s_waitcnt vmcnt(0)" ::: "memory");
}

// ---- 16 x dwordx4 system-scope loads (LLC; bypass L1+L2 — proven R4/R6) ----
__device__ __forceinline__ void load_h16(const _Float16* aptr, half8* f) {
    asm volatile(
        "global_load_dwordx4 %0, %16, off offset:0 sc0 sc1\n\t"
        "global_load_dwordx4 %1, %16, off offset:64 sc0 sc1\n\t"
        "global_load_dwordx4 %2, %16, off offset:128 sc0 sc1\n\t"
        "global_load_dwordx4 %3, %16, off offset:192 sc0 sc1\n\t"
        "global_load_dwordx4 %4, %16, off offset:256 sc0 sc1\n\t"
        "global_load_dwordx4 %5, %16, off offset:320 sc0 sc1\n\t"
        "global_load_dwordx4 %6, %16, off offset:384 sc0 sc1\n\t"
        "global_load_dwordx4 %7, %16, off offset:448 sc0 sc1\n\t"
        "global_load_dwordx4 %8, %16, off offset:512 sc0 sc1\n\t"
        "global_load_dwordx4 %9, %16, off offset:576 sc0 sc1\n\t"
        "global_load_dwordx4 %10, %16, off offset:640 sc0 sc1\n\t"
        "global_load_dwordx4 %11, %16, off offset:704 sc0 sc1\n\t"
        "global_load_dwordx4 %12, %16, off offset:768 sc0 sc1\n\t"
        "global_load_dwordx4 %13, %16, off offset:832 sc0 sc1\n\t"
        "global_load_dwordx4 %14, %16, off offset:896 sc0 sc1\n\t"
        "global_load_dwordx4 %15, %16, off offset:960 sc0 sc1"
        : "=&v"(f[0]), "=&v"(f[1]), "=&v"(f[2]), "=&v"(f[3]),
          "=&v"(f[4]), "=&v"(f[5]), "=&v"(f[6]), "=&v"(f[7]),
          "=&v"(f[8]), "=&v"(f[9]), "=&v"(f[10]), "=&v"(f[11]),
          "=&v"(f[12]), "=&v"(f[13]), "=&v"(f[14]), "=&v"(f[15])
        : "v"((uint64_t)(uintptr_t)aptr)
        : "memory");
}

__device__ __forceinline__ void wait_h16(half8* f) {
    asm volatile(
        "s_waitcnt vmcnt(0)"
        : "+v"(f[0]), "+v"(f[1]), "+v"(f[2]), "+v"(f[3]),
          "+v"(f[4]), "+v"(f[5]), "+v"(f[6]), "+v"(f[7]),
          "+v"(f[8]), "+v"(f[9]), "+v"(f[10]), "+v"(f[11]),
          "+v"(f[12]), "+v"(f[13]), "+v"(f[14]), "+v"(f[15])
        :
        : "memory");
}

// ---- publish 4 consecutive-row f16 values (rows stride 1024 B), LLC scope ----
__device__ __forceinline__ void store_h4(_Float16* addr, unsigned v0, unsigned v1,
                                         unsigned v2, unsigned v3) {
    asm volatile(
        "global_store_short %0, %1, off sc0 sc1\n\t"
        "global_store_short %0, %2, off offset:1024 sc0 sc1\n\t"
        "global_store_short %0, %3, off offset:2048 sc0 sc1\n\t"
        "global_store_short %0, %4, off offset:3072 sc0 sc1"
        :: "v"((uint64_t)(uintptr_t)addr), "v"(v0), "v"(v1), "v"(v2), "v"(v3)
        : "memory");
}

// ---- flags: sc0 sc1 asm — the only poll primitive PROVEN fresh on this HW
// (R6: sc0-only polls spun 2048x stale; the sc0 sc1 fallback resolved at once).
__device__ __forceinline__ void flag_set(unsigned* p, unsigned val) {
    asm volatile("global_store_dword %0, %1, off sc0 sc1"
                 :: "v"((uint64_t)(uintptr_t)p), "v"(val) : "memory");
}

__device__ __forceinline__ unsigned flag_get(const unsigned* p) {
    unsigned v;
    asm volatile("global_load_dword %0, %1, off sc0 sc1\n\ts_waitcnt vmcnt(0)"
                 : "=v"(v) : "v"((uint64_t)(uintptr_t)p) : "memory");
    return v;
}

__device__ __forceinline__ void poll_flags(const unsigned* base, int lane, unsigned tgt) {
    const unsigned* p = base + (lane & 31);
    while (!__all((int)(flag_get(p) >= tgt))) {}
}

// ---------------- cast x to f16 + zero pub/flag state ------------------------
__global__ void cast_init_kernel(const float* __restrict__ x,
                                 _Float16* __restrict__ xh,
                                 _Float16* __restrict__ h1pub,
                                 _Float16* __restrict__ h2pub,
                                 unsigned int* __restrict__ gbar) {
    size_t i      = (size_t)blockIdx.x * blockDim.x + threadIdx.x;
    size_t stride = (size_t)gridDim.x * blockDim.x;
    for (size_t idx = i; idx < (size_t)B_ * T_ * F_; idx += stride)
        xh[idx] = (_Float16)x[idx];
    for (size_t idx = i; idx < (size_t)3 * BU; idx += stride)
        h1pub[idx] = (_Float16)0.f;
    for (size_t idx = i; idx < (size_t)2 * BU; idx += stride)
        h2pub[idx] = (_Float16)0.f;
    if (blockIdx.x == 0)
        for (int idx = threadIdx.x; idx < 2048; idx += blockDim.x)
            gbar[idx] = 0u;
}

// ---------------- transpose+cast weights: (K,1536) f32 -> (1536,K) f16 -------
__global__ void transpose_cast_kernel(const float* __restrict__ in,
                                      _Float16* __restrict__ out, int K) {
    __shared__ float tile[32][33];
    int n0 = blockIdx.x * 32;
    int k0 = blockIdx.y * 32;
    int tx = threadIdx.x, ty = threadIdx.y;   // block (32, 8)
#pragma unroll
    for (int i = 0; i < 4; ++i)
        tile[ty + i * 8][tx] = in[(size_t)(k0 + ty + i * 8) * G3 + (n0 + tx)];
    __syncthreads();
#pragma unroll
    for (int i = 0; i < 4; ++i)
        out[(size_t)(n0 + ty + i * 8) * K + (k0 + tx)] =
            (_Float16)tile[tx][ty + i * 8];
}

// ---------------- GX1 = x @ W1 ----------------------------------------------
__global__ __launch_bounds__(256) void gemm_gx1_kernel(
    const _Float16* __restrict__ xh,
    const _Float16* __restrict__ w1t,
    _Float16* __restrict__ gx1) {
    int bx = blockIdx.x;          // 12288 = 1024 m-blocks * 12 n-blocks
    int mb = bx / 12, nb = bx % 12;
    int wave = threadIdx.x >> 6, lane = threadIdx.x & 63;
    int wm = wave >> 1, wn = wave & 1;
    int am = lane & 15, aq = lane >> 4;

    half8 af[2][4];
#pragma unroll
    for (int mt = 0; mt < 2; ++mt) {
        int mo = mb * 64 + wm * 32 + mt * 16 + am;
        int b = mo & 127, t = mo >> 7;
        const _Float16* ap = xh + ((size_t)b * T_ + t) * F_ + aq * 8;
#pragma unroll
        for (int kc = 0; kc < 4; ++kc)
            af[mt][kc] = *(const half8*)(ap + kc * 32);
    }

#pragma unroll
    for (int nt = 0; nt < 4; ++nt) {
        int n0 = nb * 128 + wn * 64 + nt * 16;
        f32x4 acc0 = {0.f, 0.f, 0.f, 0.f};
        f32x4 acc1 = {0.f, 0.f, 0.f, 0.f};
#pragma unroll
        for (int kc = 0; kc < 4; ++kc) {
            half8 bf = *(const half8*)(w1t + (size_t)(n0 + am) * F_ + kc * 32 + aq * 8);
            acc0 = __builtin_amdgcn_mfma_f32_16x16x32_f16(af[0][kc], bf, acc0, 0, 0, 0);
            acc1 = __builtin_amdgcn_mfma_f32_16x16x32_f16(af[1][kc], bf, acc1, 0, 0, 0);
        }
        int col = lane & 15, rb = (lane >> 4) * 4;
        int mbase0 = mb * 64 + wm * 32 + 0 * 16;
        int mbase1 = mb * 64 + wm * 32 + 1 * 16;
#pragma unroll
        for (int i = 0; i < 4; ++i) {
            gx1[(size_t)(mbase0 + rb + i) * G3 + n0 + col] = (_Float16)acc0[i];
            gx1[(size_t)(mbase1 + rb + i) * G3 + n0 + col] = (_Float16)acc1[i];
        }
    }
}

// ---------------- persistent 2-layer GRU main loop (3 waves) -----------------
// wave0: rec1 mfma + in-lane L1 combine + publish h1_r + flag1=r+1  (r 0..511)
// wave1: gx2_{r-1} mfma -> LDS scratch[r&1]                         (r 1..512)
// wave2: rec2 mfma + in-lane L2 combine (gx2 from scratch[(r-1)&1])
//        + publish h2_{r-2} + flag2=r-1                             (r 2..513)
// KEY INVARIANT: everything consumed at round r was published at round r-1
// (no intra-round cross-WG chains — R8's mistake). One __syncthreads/round.
// WAR: h1 3-deep (flag1>=r proves all WGs passed barrier end-of-(r-2), so
// h1_{r-3} readers are done). h2 2-deep (flag2>=r-2 set after the remote
// wave2's vm_drain, which covers its h2_{r-4} loads).
__global__ __launch_bounds__(192, 1) void gru_persist_kernel(
    const _Float16* __restrict__ gx1,
    const _Float16* __restrict__ u1t,
    const _Float16* __restrict__ w2t,
    const _Float16* __restrict__ u2t,
    const float* __restrict__ bi1, const float* __restrict__ br1,
    const float* __restrict__ bi2, const float* __restrict__ br2,
    _Float16* __restrict__ h1pub,      // 3 x (128,512) f16
    _Float16* __restrict__ h2pub,      // 2 x (128,512) f16
    float* __restrict__ h2fin,         // (128,512) f32
    unsigned int* __restrict__ gbar) {
    __shared__ float scr[2 * 3 * 16 * 17];   // gx2 scratch, parity dbuf, 6528 B

    const int tid  = threadIdx.x;
    const int bx   = blockIdx.x;
    const int grp  = bx & 7;
    const int jj   = bx >> 3;
    const int wave = tid >> 6, lane = tid & 63;
    const int row0 = grp * MB;
    const int u0   = jj * UC;

    unsigned* flag1 = gbar + 512  + (size_t)grp * 32;
    unsigned* flag2 = gbar + 1024 + (size_t)grp * 32;
    unsigned* myflag1 = flag1 + jj;
    unsigned* myflag2 = flag2 + jj;

    const int col = lane & 15;
    const int rb4 = (lane >> 4) * 4;
    const int aq  = lane >> 4;
    const size_t a_elem = (size_t)(row0 + col) * U_ + aq * 8;
    const int u = u0 + col;

    // loop-invariant weight fragments (48 half8/wave)
    const _Float16* wsrc = (wave == 0) ? u1t : (wave == 1) ? w2t : u2t;
    half8 bfr[3][16];
#pragma unroll
    for (int g = 0; g < 3; ++g)
#pragma unroll
        for (int kc = 0; kc < 16; ++kc)
            bfr[g][kc] = *(const half8*)(
                wsrc + (size_t)(g * U_ + u0 + col) * U_ + kc * 32 + aq * 8);

    // combine constants (wave0: layer1, wave2: layer2)
    float zb = 0.f, rb_ = 0.f, hbi = 0.f, hbr = 0.f;
    _Float16 pgz[4], pgr[4], pgh[4];
    if (wave == 0) {
        zb  = bi1[u] + br1[u];
        rb_ = bi1[U_ + u] + br1[U_ + u];
        hbi = bi1[2 * U_ + u];
        hbr = br1[2 * U_ + u];
        const _Float16* g0 = gx1 + ((size_t)0 * B_ + row0 + rb4) * G3;
#pragma unroll
        for (int i = 0; i < 4; ++i) {
            pgz[i] = g0[(size_t)i * G3 + u];
            pgr[i] = g0[(size_t)i * G3 + U_ + u];
            pgh[i] = g0[(size_t)i * G3 + 2 * U_ + u];
        }
    } else if (wave == 2) {
        zb  = bi2[u] + br2[u];
        rb_ = bi2[U_ + u] + br2[U_ + u];
        hbi = bi2[2 * U_ + u];
        hbr = br2[2 * U_ + u];
    }

    float st[4] = {0.f, 0.f, 0.f, 0.f};   // wave0: h1 state; wave2: h2 state

    int wr3 = 0, rd3 = 2;   // h1 slots: write r%3, read (r+2)%3 (= h1_{r-1})
    for (int r = 0; r <= T_ + 1; ++r) {
        if (wave == 0) {
            if (r < T_) {
                poll_flags(flag1, lane, (unsigned)r);
                // prefetch next round's gx1 AFTER the poll (its HBM latency
                // hides under the h-load; completed by wait_h16)
                _Float16 ngz[4], ngr[4], ngh[4];
                bool pf = (r + 1 < T_);
                if (pf) {
                    const _Float16* g = gx1 + ((size_t)(r + 1) * B_ + row0 + rb4) * G3;
#pragma unroll
                    for (int i = 0; i < 4; ++i) {
                        ngz[i] = g[(size_t)i * G3 + u];
                        ngr[i] = g[(size_t)i * G3 + U_ + u];
                        ngh[i] = g[(size_t)i * G3 + 2 * U_ + u];
                    }
                }
                half8 f[16];
                load_h16(h1pub + (size_t)rd3 * BU + a_elem, f);
                wait_h16(f);
                f32x4 a0 = {0.f, 0.f, 0.f, 0.f};
                f32x4 a1 = {0.f, 0.f, 0.f, 0.f};
                f32x4 a2 = {0.f, 0.f, 0.f, 0.f};
#pragma unroll
                for (int kc = 0; kc < 16; ++kc) {
                    a0 = __builtin_amdgcn_mfma_f32_16x16x32_f16(f[kc], bfr[0][kc], a0, 0, 0, 0);
                    a1 = __builtin_amdgcn_mfma_f32_16x16x32_f16(f[kc], bfr[1][kc], a1, 0, 0, 0);
                    a2 = __builtin_amdgcn_mfma_f32_16x16x32_f16(f[kc], bfr[2][kc], a2, 0, 0, 0);
                }
                unsigned pv[4];
#pragma unroll
                for (int i = 0; i < 4; ++i) {
                    float z  = sigmoidf_((float)pgz[i] + a0[i] + zb);
                    float rg = sigmoidf_((float)pgr[i] + a1[i] + rb_);
                    float hh = fmaxf(0.f, (float)pgh[i] + hbi + rg * (a2[i] + hbr));
                    st[i] = z * st[i] + (1.f - z) * hh;
                    HU16 c; c.h = (_Float16)st[i]; pv[i] = c.us;
                }
                _Float16* dst = h1pub + (size_t)wr3 * BU +
                                (size_t)(row0 + rb4) * U_ + u;
                store_h4(dst, pv[0], pv[1], pv[2], pv[3]);
                vm_drain();
                if (lane == 0) flag_set(myflag1, (unsigned)(r + 1));
                if (pf) {
#pragma unroll
                    for (int i = 0; i < 4; ++i) {
                        pgz[i] = ngz[i]; pgr[i] = ngr[i]; pgh[i] = ngh[i];
                    }
                }
            }
        } else if (wave == 1) {
            if (r >= 1 && r <= T_) {
                poll_flags(flag1, lane, (unsigned)r);
                half8 f[16];
                load_h16(h1pub + (size_t)rd3 * BU + a_elem, f);
                wait_h16(f);
                f32x4 a0 = {0.f, 0.f, 0.f, 0.f};
                f32x4 a1 = {0.f, 0.f, 0.f, 0.f};
                f32x4 a2 = {0.f, 0.f, 0.f, 0.f};
#pragma unroll
                for (int kc = 0; kc < 16; ++kc) {
                    a0 = __builtin_amdgcn_mfma_f32_16x16x32_f16(f[kc], bfr[0][kc], a0, 0, 0, 0);
                    a1 = __builtin_amdgcn_mfma_f32_16x16x32_f16(f[kc], bfr[1][kc], a1, 0, 0, 0);
                    a2 = __builtin_amdgcn_mfma_f32_16x16x32_f16(f[kc], bfr[2][kc], a2, 0, 0, 0);
                }
                float* sp = scr + (size_t)(r & 1) * 3 * 272;
#pragma unroll
                for (int i = 0; i < 4; ++i) {
                    sp[0 * 272 + (rb4 + i) * 17 + col] = a0[i];
                    sp[1 * 272 + (rb4 + i) * 17 + col] = a1[i];
                    sp[2 * 272 + (rb4 + i) * 17 + col] = a2[i];
                }
            }
        } else {
            if (r >= 2) {
                int s = r - 2;
                poll_flags(flag2, lane, (unsigned)(r - 2));
                half8 f[16];
                load_h16(h2pub + (size_t)((r - 1) & 1) * BU + a_elem, f);  // h2_{r-3}
                wait_h16(f);
                f32x4 a0 = {0.f, 0.f, 0.f, 0.f};
                f32x4 a1 = {0.f, 0.f, 0.f, 0.f};
                f32x4 a2 = {0.f, 0.f, 0.f, 0.f};
#pragma unroll
                for (int kc = 0; kc < 16; ++kc) {
                    a0 = __builtin_amdgcn_mfma_f32_16x16x32_f16(f[kc], bfr[0][kc], a0, 0, 0, 0);
                    a1 = __builtin_amdgcn_mfma_f32_16x16x32_f16(f[kc], bfr[1][kc], a1, 0, 0, 0);
                    a2 = __builtin_amdgcn_mfma_f32_16x16x32_f16(f[kc], bfr[2][kc], a2, 0, 0, 0);
                }
                const float* sp = scr + (size_t)((r - 1) & 1) * 3 * 272;  // gx2_{r-2}
                unsigned pv[4];
#pragma unroll
                for (int i = 0; i < 4; ++i) {
                    int ro = (rb4 + i) * 17 + col;
                    float z  = sigmoidf_(sp[0 * 272 + ro] + a0[i] + zb);
                    float rg = sigmoidf_(sp[1 * 272 + ro] + a1[i] + rb_);
                    float hh = fmaxf(0.f, sp[2 * 272 + ro] + hbi + rg * (a2[i] + hbr));
                    st[i] = z * st[i] + (1.f - z) * hh;
                    HU16 c; c.h = (_Float16)st[i]; pv[i] = c.us;
                }
                _Float16* dst = h2pub + (size_t)(s & 1) * BU +
                                (size_t)(row0 + rb4) * U_ + u;
                store_h4(dst, pv[0], pv[1], pv[2], pv[3]);
                vm_drain();
                if (lane == 0) flag_set(myflag2, (unsigned)(s + 1));
                if (s == T_ - 1) {
#pragma unroll
                    for (int i = 0; i < 4; ++i)
                        h2fin[(size_t)(row0 + rb4 + i) * U_ + u] = st[i];
                }
            }
        }
        __syncthreads();
        wr3 = (wr3 == 2) ? 0 : wr3 + 1;
        rd3 = (rd3 == 2) ? 0 : rd3 + 1;
    }
}

// ---------------- head: out = h2_final @ Wd + bd -----------------------------
__global__ void head_kernel(const float* __restrict__ h2fin,
                            const float* __restrict__ Wd,
                            const float* __restrict__ bd,
                            float* __restrict__ out) {
    int b = blockIdx.x;
    int lane = threadIdx.x;   // 64
    float s = 0.f;
#pragma unroll
    for (int u = lane; u < U_; u += 64)
        s += h2fin[(size_t)b * U_ + u] * Wd[u];
#pragma unroll
    for (int off = 32; off > 0; off >>= 1)
        s += __shfl_down(s, off, 64);
    if (lane == 0) out[b] = s + bd[0];
}

// ---------------- launch -----------------------------------------------------
extern "C" void kernel_launch(void* const* d_in, const int* in_sizes, int n_in,
                              void* d_out, int out_size, void* d_ws, size_t ws_size,
                              hipStream_t stream) {
    (void)in_sizes; (void)n_in; (void)out_size; (void)ws_size;

    const float* x   = (const float*)d_in[0];
    const float* W1  = (const float*)d_in[1];
    const float* U1  = (const float*)d_in[2];
    const float* bi1 = (const float*)d_in[3];
    const float* br1 = (const float*)d_in[4];
    const float* W2  = (const float*)d_in[5];
    const float* U2  = (const float*)d_in[6];
    const float* bi2 = (const float*)d_in[7];
    const float* br2 = (const float*)d_in[8];
    const float* Wd  = (const float*)d_in[9];
    const float* bd  = (const float*)d_in[10];

    char* w = (char*)d_ws;
    constexpr size_t OFF_XH   = 0;
    constexpr size_t OFF_W1T  = OFF_XH  + (size_t)B_ * T_ * F_ * 2;
    constexpr size_t OFF_U1T  = OFF_W1T + (size_t)G3 * F_ * 2;
    constexpr size_t OFF_W2T  = OFF_U1T + (size_t)G3 * U_ * 2;
    constexpr size_t OFF_U2T  = OFF_W2T + (size_t)G3 * U_ * 2;
    constexpr size_t OFF_GX1  = OFF_U2T + (size_t)G3 * U_ * 2;
    constexpr size_t OFF_H1P  = OFF_GX1 + (size_t)T_ * B_ * G3 * 2;
    constexpr size_t OFF_H2P  = OFF_H1P + (size_t)3 * BU * 2;
    constexpr size_t OFF_H2F  = OFF_H2P + (size_t)2 * BU * 2;
    constexpr size_t OFF_BAR  = OFF_H2F + (size_t)BU * 4;

    _Float16* xh   = (_Float16*)(w + OFF_XH);
    _Float16* w1t  = (_Float16*)(w + OFF_W1T);
    _Float16* u1t  = (_Float16*)(w + OFF_U1T);
    _Float16* w2t  = (_Float16*)(w + OFF_W2T);
    _Float16* u2t  = (_Float16*)(w + OFF_U2T);
    _Float16* gx1  = (_Float16*)(w + OFF_GX1);
    _Float16* h1p  = (_Float16*)(w + OFF_H1P);
    _Float16* h2p  = (_Float16*)(w + OFF_H2P);
    float*    h2f  = (float*)   (w + OFF_H2F);
    unsigned int* gbar = (unsigned int*)(w + OFF_BAR);

    cast_init_kernel<<<1024, 256, 0, stream>>>(x, xh, h1p, h2p, gbar);

    dim3 tb(32, 8);
    transpose_cast_kernel<<<dim3(48, 4),  tb, 0, stream>>>(W1, w1t, F_);
    transpose_cast_kernel<<<dim3(48, 16), tb, 0, stream>>>(U1, u1t, U_);
    transpose_cast_kernel<<<dim3(48, 16), tb, 0, stream>>>(W2, w2t, U_);
    transpose_cast_kernel<<<dim3(48, 16), tb, 0, stream>>>(U2, u2t, U_);

    gemm_gx1_kernel<<<12288, 256, 0, stream>>>(xh, w1t, gx1);

    gru_persist_kernel<<<256, 192, 0, stream>>>(gx1, u1t, w2t, u2t,
                                                bi1, br1, bi2, br2,
                                                h1p, h2p, h2f, gbar);

    head_kernel<<<128, 64, 0, stream>>>(h2f, Wd, bd, (float*)d_out);
}